// Round 19
// baseline (166.029 us; speedup 1.0000x reference)
//
#include <hip/hip_runtime.h>

typedef float f32x4 __attribute__((ext_vector_type(4)));
typedef __bf16 bf16x8 __attribute__((ext_vector_type(8)));
typedef unsigned int u32x4 __attribute__((ext_vector_type(4)));

#define TT 32   // atoms per block tile

// packed bf16 weight planes in d_ws after dEdD (ushort element offsets)
#define PW1_HI   0
#define PW1_LO   8192
#define PW2_HI   16384
#define PW2_LO   32768
#define PW2T_HI  49152
#define PW2T_LO  65536
#define PW1T_HI  81920
#define PW1T_LO  90112
#define PW_SLOTS 49152

__global__ void zero_kernel(float* __restrict__ p, int n) {
    int i = blockIdx.x * blockDim.x + threadIdx.x;
    if (i < n) p[i] = 0.f;
}

__device__ __forceinline__ void bf16split(float x, unsigned short& hi, unsigned short& lo) {
    unsigned u = __float_as_uint(x);
    unsigned r = (u + 0x7FFFu + ((u >> 16) & 1u)) >> 16;   // RNE to bf16
    hi = (unsigned short)r;
    float hf = __uint_as_float(r << 16);
    unsigned u2 = __float_as_uint(x - hf);                 // exact residual
    unsigned r2 = (u2 + 0x7FFFu + ((u2 >> 16) & 1u)) >> 16;
    lo = (unsigned short)r2;
}

__device__ __forceinline__ void split2(float a, float b, unsigned& hw, unsigned& lw) {
    unsigned ua = __float_as_uint(a);
    unsigned ra = (ua + 0x7FFFu + ((ua >> 16) & 1u)) >> 16;
    unsigned ua2 = __float_as_uint(a - __uint_as_float(ra << 16));
    unsigned la = (ua2 + 0x7FFFu + ((ua2 >> 16) & 1u)) >> 16;
    unsigned ub = __float_as_uint(b);
    unsigned rb = (ub + 0x7FFFu + ((ub >> 16) & 1u)) >> 16;
    unsigned ub2 = __float_as_uint(b - __uint_as_float(rb << 16));
    unsigned lb = (ub2 + 0x7FFFu + ((ub2 >> 16) & 1u)) >> 16;
    hw = ra | (rb << 16);
    lw = la | (lb << 16);
}

// ---------------- weight pre-pack: fragment-ordered bf16 hi/lo planes ----------------
__global__ void pack_weights(const float* __restrict__ W1, const float* __restrict__ W2,
                             unsigned short* __restrict__ pw) {
    int s = blockIdx.x * blockDim.x + threadIdx.x;
    if (s >= PW_SLOTS) return;
    int slot, NS, hiOff, loOff; const float* src; bool tr;
    if (s < 8192)       { slot = s;         NS = 8; hiOff = PW1_HI;  loOff = PW1_LO;  tr = false; src = W1; }
    else if (s < 24576) { slot = s - 8192;  NS = 8; hiOff = PW2_HI;  loOff = PW2_LO;  tr = false; src = W2; }
    else if (s < 40960) { slot = s - 24576; NS = 8; hiOff = PW2T_HI; loOff = PW2T_LO; tr = true;  src = W2; }
    else                { slot = s - 40960; NS = 4; hiOff = PW1T_HI; loOff = PW1T_LO; tr = true;  src = W1; }
    int j = slot & 7, lane = (slot >> 3) & 63, rest = slot >> 9;
    int ns = rest % NS, ks = rest / NS;
    int k = ks * 32 + ((lane >> 4) & 3) * 8 + j;
    int n = ns * 16 + (lane & 15);
    float v = tr ? src[n * 128 + k] : src[k * 128 + n];
    unsigned short hi, lo;
    bf16split(v, hi, lo);
    pw[hiOff + slot] = hi;
    pw[loOff + slot] = lo;
}

// ---------------- fused MLP fwd+bwd via MFMA (LDS-staged weights) ----------------
// R17 lesson: mlp is bound by B-operand L2/LLC latency (all pipes idle; per-XCD
// L2 non-coherence means pw reads miss to LLC). Fix: stage each GEMM's packed
// planes into LDS (coalesced bulk copy, then conflict-free contiguous
// ds_read_b128 fragment loads at ~120cy instead of ~500cy global).
// LDS: 8(xs) + 16(h1s) + 16(g2s) + 64(wb) = 104 KB -> 1 block/CU, no reg cap.
__global__ __launch_bounds__(256, 1) void mlp_mfma(
    const float* __restrict__ x,
    const float* __restrict__ b1, const float* __restrict__ b2,
    const float* __restrict__ W3, const float* __restrict__ b3,
    const int* __restrict__ indices,
    const unsigned short* __restrict__ pw,
    float* __restrict__ energy, float* __restrict__ dEdD, int natoms)
{
    __shared__ float xs[TT * 64];                       // 8 KB, swizzled (key=row&7)
    __shared__ float h1s[TT * 128];                     // 16 KB: h1, later dz1
    __shared__ float g2s[TT * 128];                     // 16 KB
    __shared__ __align__(16) unsigned short wbH[16384]; // 32 KB: current-phase hi plane
    __shared__ __align__(16) unsigned short wbL[16384]; // 32 KB: current-phase lo plane

    const int tid = threadIdx.x;
    const int l   = tid & 63;
    const int w   = tid >> 6;
    const int col = l & 15;
    const int rg  = l >> 4;
    const int msub = w >> 1;
    const int half = w & 1;
    const int a0 = blockIdx.x * TT;
    const int mrow = msub * 16 + col;

    // ---- stage x tile (swizzled) + W1 planes ----
    #pragma unroll
    for (int p = 0; p < 2; ++p) {
        int idx = tid + p * 256;
        int r = idx >> 4, c = idx & 15;
        int a = a0 + r;
        f32x4 v = {0.f, 0.f, 0.f, 0.f};
        if (a < natoms) v = *(const f32x4*)(x + (size_t)a * 64 + c * 4);
        *(f32x4*)(xs + r * 64 + ((c ^ (r & 7)) << 2)) = v;
    }

    auto stageW = [&](int hiOff, int loOff, int chunks) {   // chunks = count/8
        for (int i = tid; i < chunks; i += 256) {
            u32x4 vh = *(const u32x4*)(pw + hiOff + i * 8);
            u32x4 vl = *(const u32x4*)(pw + loOff + i * 8);
            *(u32x4*)(wbH + i * 8) = vh;
            *(u32x4*)(wbL + i * 8) = vl;
        }
    };

    stageW(PW1_HI, PW1_LO, 1024);    // W1: 8192 ushorts/plane
    __syncthreads();

    auto loadA = [&](const float* buf, int stride, int kbase, bf16x8& ah, bf16x8& al) {
        int key = mrow & 7;
        int c0 = kbase >> 2;
        f32x4 f0 = *(const f32x4*)(buf + mrow * stride + (((c0    ) ^ key) << 2));
        f32x4 f1 = *(const f32x4*)(buf + mrow * stride + (((c0 + 1) ^ key) << 2));
        u32x4 H, L;
        unsigned hw, lw;
        split2(f0[0], f0[1], hw, lw); H[0] = hw; L[0] = lw;
        split2(f0[2], f0[3], hw, lw); H[1] = hw; L[1] = lw;
        split2(f1[0], f1[1], hw, lw); H[2] = hw; L[2] = lw;
        split2(f1[2], f1[3], hw, lw); H[3] = hw; L[3] = lw;
        ah = __builtin_bit_cast(bf16x8, H);
        al = __builtin_bit_cast(bf16x8, L);
    };
    auto loadBL = [&](int NS, int ks, int nsub, bf16x8& bh, bf16x8& bl) {
        int idx = ((ks * NS + nsub) * 64 + l) * 8;      // contiguous: conflict-free b128
        bh = __builtin_bit_cast(bf16x8, *(const u32x4*)(wbH + idx));
        bl = __builtin_bit_cast(bf16x8, *(const u32x4*)(wbL + idx));
    };

    bf16x8 ah0, al0, ah1, al1, ah2, al2, ah3, al3;

    #define KSTEP(NS, KS, NSUB, AH, AL)                                            \
        {                                                                          \
            bf16x8 bh, bl;                                                         \
            loadBL(NS, KS, NSUB, bh, bl);                                          \
            acc = __builtin_amdgcn_mfma_f32_16x16x32_bf16(AH, bh, acc, 0, 0, 0);   \
            acc = __builtin_amdgcn_mfma_f32_16x16x32_bf16(AL, bh, acc, 0, 0, 0);   \
            acc = __builtin_amdgcn_mfma_f32_16x16x32_bf16(AH, bl, acc, 0, 0, 0);   \
        }

    // ---- GEMM1: z1 = X@W1 + b1; h1 = sigm ----
    loadA(xs, 64,  0 + rg * 8, ah0, al0);
    loadA(xs, 64, 32 + rg * 8, ah1, al1);
    #pragma unroll
    for (int ns = 0; ns < 4; ++ns) {
        int nsub = half * 4 + ns, n0 = nsub * 16;
        float bv = b1[n0 + col];
        f32x4 acc = {bv, bv, bv, bv};
        KSTEP(8, 0, nsub, ah0, al0)
        KSTEP(8, 1, nsub, ah1, al1)
        #pragma unroll
        for (int r2 = 0; r2 < 4; ++r2) {
            int m = msub * 16 + rg * 4 + r2, k = n0 + col;
            float h = 1.f / (1.f + expf(-acc[r2]));
            h1s[m * 128 + ((((k >> 2)) ^ (m & 7)) << 2) + (k & 3)] = h;
        }
    }
    __syncthreads();                  // h1s ready; all GEMM1 wb reads done

    stageW(PW2_HI, PW2_LO, 2048);     // W2: 16384 ushorts/plane
    __syncthreads();

    // ---- GEMM2: z2 = h1@W2 + b2; h2, energy, g2 ----
    loadA(h1s, 128,  0 + rg * 8, ah0, al0);
    loadA(h1s, 128, 32 + rg * 8, ah1, al1);
    loadA(h1s, 128, 64 + rg * 8, ah2, al2);
    loadA(h1s, 128, 96 + rg * 8, ah3, al3);
    float e0 = 0.f, e1 = 0.f, e2 = 0.f, e3 = 0.f;
    #pragma unroll
    for (int ns = 0; ns < 4; ++ns) {
        int nsub = half * 4 + ns, n0 = nsub * 16;
        float bv = b2[n0 + col];
        f32x4 acc = {bv, bv, bv, bv};
        KSTEP(8, 0, nsub, ah0, al0)
        KSTEP(8, 1, nsub, ah1, al1)
        KSTEP(8, 2, nsub, ah2, al2)
        KSTEP(8, 3, nsub, ah3, al3)
        float w3v = W3[n0 + col];
        #pragma unroll
        for (int r2 = 0; r2 < 4; ++r2) {
            float h2 = 1.f / (1.f + expf(-acc[r2]));
            float ec = h2 * w3v;
            if (r2 == 0) e0 += ec; else if (r2 == 1) e1 += ec;
            else if (r2 == 2) e2 += ec; else e3 += ec;
            float g = w3v * h2 * (1.f - h2);
            int m = msub * 16 + rg * 4 + r2, k = n0 + col;
            g2s[m * 128 + ((((k >> 2)) ^ (m & 7)) << 2) + (k & 3)] = g;
        }
    }
    {
        e0 += __shfl_xor(e0, 1); e0 += __shfl_xor(e0, 2); e0 += __shfl_xor(e0, 4); e0 += __shfl_xor(e0, 8);
        e1 += __shfl_xor(e1, 1); e1 += __shfl_xor(e1, 2); e1 += __shfl_xor(e1, 4); e1 += __shfl_xor(e1, 8);
        e2 += __shfl_xor(e2, 1); e2 += __shfl_xor(e2, 2); e2 += __shfl_xor(e2, 4); e2 += __shfl_xor(e2, 8);
        e3 += __shfl_xor(e3, 1); e3 += __shfl_xor(e3, 2); e3 += __shfl_xor(e3, 4); e3 += __shfl_xor(e3, 8);
        if (col == 0) {
            float b3v = (half == 0) ? b3[0] : 0.f;
            int ab = a0 + msub * 16 + rg * 4;
            if (ab + 0 < natoms) atomicAdd(&energy[indices[ab + 0]], e0 + b3v);
            if (ab + 1 < natoms) atomicAdd(&energy[indices[ab + 1]], e1 + b3v);
            if (ab + 2 < natoms) atomicAdd(&energy[indices[ab + 2]], e2 + b3v);
            if (ab + 3 < natoms) atomicAdd(&energy[indices[ab + 3]], e3 + b3v);
        }
    }
    __syncthreads();                  // g2s ready; GEMM2 wb reads done

    stageW(PW2T_HI, PW2T_LO, 2048);   // W2T
    __syncthreads();

    // ---- GEMM3: dh1 = g2@W2^T; dz1 = dh1*h1*(1-h1) in-place ----
    loadA(g2s, 128,  0 + rg * 8, ah0, al0);
    loadA(g2s, 128, 32 + rg * 8, ah1, al1);
    loadA(g2s, 128, 64 + rg * 8, ah2, al2);
    loadA(g2s, 128, 96 + rg * 8, ah3, al3);
    #pragma unroll
    for (int ns = 0; ns < 4; ++ns) {
        int nsub = half * 4 + ns, n0 = nsub * 16;
        f32x4 acc = {0.f, 0.f, 0.f, 0.f};
        KSTEP(8, 0, nsub, ah0, al0)
        KSTEP(8, 1, nsub, ah1, al1)
        KSTEP(8, 2, nsub, ah2, al2)
        KSTEP(8, 3, nsub, ah3, al3)
        #pragma unroll
        for (int r2 = 0; r2 < 4; ++r2) {
            int m = msub * 16 + rg * 4 + r2, k = n0 + col;
            int off = m * 128 + ((((k >> 2)) ^ (m & 7)) << 2) + (k & 3);
            float hv = h1s[off];
            h1s[off] = acc[r2] * hv * (1.f - hv);
        }
    }
    __syncthreads();                  // dz1 ready; GEMM3 wb reads done

    stageW(PW1T_HI, PW1T_LO, 1024);   // W1T
    __syncthreads();

    // ---- GEMM4: dEdD = dz1@W1^T ----
    loadA(h1s, 128,  0 + rg * 8, ah0, al0);
    loadA(h1s, 128, 32 + rg * 8, ah1, al1);
    loadA(h1s, 128, 64 + rg * 8, ah2, al2);
    loadA(h1s, 128, 96 + rg * 8, ah3, al3);
    #pragma unroll
    for (int ns = 0; ns < 2; ++ns) {
        int nsub = half * 2 + ns, n0 = nsub * 16;
        f32x4 acc = {0.f, 0.f, 0.f, 0.f};
        KSTEP(4, 0, nsub, ah0, al0)
        KSTEP(4, 1, nsub, ah1, al1)
        KSTEP(4, 2, nsub, ah2, al2)
        KSTEP(4, 3, nsub, ah3, al3)
        #pragma unroll
        for (int r2 = 0; r2 < 4; ++r2) {
            int a = a0 + msub * 16 + rg * 4 + r2;
            if (a < natoms) dEdD[(size_t)a * 64 + n0 + col] = acc[r2];
        }
    }
    #undef KSTEP
}

// ---------------- force accumulation (unchanged, proven) ----------------
__global__ __launch_bounds__(256) void force_kernel(
    const float* __restrict__ xd,
    const int* __restrict__ unique_i, const int* __restrict__ unique_j,
    const float* __restrict__ dEdD,
    float* __restrict__ forces, int nderiv)
{
    const int tid = threadIdx.x;
    const int lane = tid & 63;
    const int wib = tid >> 6;
    const int gwave = blockIdx.x * 4 + wib;
    const int nwaves = gridDim.x * 4;
    const int sub = lane >> 4;
    const int t = lane & 15;
    const int ngroups = (nderiv + 3) >> 2;

    for (int g = gwave; g < ngroups; g += nwaves) {
        const int r = g * 4 + sub;
        float p = 0.f;
        int jdst = 0, ax = 0;
        const bool valid = (r < nderiv);
        if (valid) {
            const int ai = unique_i[r];
            const float4 v = ((const float4*)(xd   + (size_t)r  * 64))[t];
            const float4 wv = ((const float4*)(dEdD + (size_t)ai * 64))[t];
            p = v.x * wv.x + v.y * wv.y + v.z * wv.z + v.w * wv.w;
            jdst = unique_j[r];
            ax = r % 3;   // axis = tile([0,1,2]) by construction
        }
        p += __shfl_xor(p, 1);
        p += __shfl_xor(p, 2);
        p += __shfl_xor(p, 4);
        p += __shfl_xor(p, 8);
        if (t == 0 && valid) atomicAdd(&forces[jdst * 3 + ax], p);
    }
}

extern "C" void kernel_launch(void* const* d_in, const int* in_sizes, int n_in,
                              void* d_out, int out_size, void* d_ws, size_t ws_size,
                              hipStream_t stream) {
    const float* x        = (const float*)d_in[0];
    const float* xd       = (const float*)d_in[1];
    const int*   indices  = (const int*)d_in[2];
    const int*   unique_i = (const int*)d_in[6];
    const int*   unique_j = (const int*)d_in[7];
    const float* W1       = (const float*)d_in[8];
    const float* b1       = (const float*)d_in[9];
    const float* W2       = (const float*)d_in[10];
    const float* b2       = (const float*)d_in[11];
    const float* W3       = (const float*)d_in[12];
    const float* b3       = (const float*)d_in[13];

    const int natoms = in_sizes[2];
    const int nconf  = in_sizes[3];
    const int nderiv = in_sizes[6];

    float* out    = (float*)d_out;
    float* energy = out;
    float* forces = out + nconf;
    float* dEdD   = (float*)d_ws;
    unsigned short* pw = (unsigned short*)((char*)d_ws + (size_t)natoms * 64 * 4);

    const int ntiles = (natoms + TT - 1) / TT;

    zero_kernel<<<(out_size + 255) / 256, 256, 0, stream>>>(out, out_size);
    pack_weights<<<(PW_SLOTS + 255) / 256, 256, 0, stream>>>(W1, W2, pw);
    mlp_mfma<<<ntiles, 256, 0, stream>>>(x, b1, b2, W3, b3, indices, pw,
                                         energy, dEdD, natoms);
    force_kernel<<<2048, 256, 0, stream>>>(xd, unique_i, unique_j, dEdD,
                                           forces, nderiv);
}

// Round 20
// 132.447 us; speedup vs baseline: 1.2536x; 1.2536x over previous
//
#include <hip/hip_runtime.h>

typedef float f32x4 __attribute__((ext_vector_type(4)));
typedef __bf16 bf16x8 __attribute__((ext_vector_type(8)));
typedef unsigned int u32x4 __attribute__((ext_vector_type(4)));

#define TT 32   // atoms per block tile

// packed bf16 weight planes in d_ws after dEdD (ushort element offsets)
#define PW1_HI   0
#define PW1_LO   8192
#define PW2_HI   16384
#define PW2_LO   32768
#define PW2T_HI  49152
#define PW2T_LO  65536
#define PW1T_HI  81920
#define PW1T_LO  90112
#define PW_SLOTS 49152

__device__ __forceinline__ void bf16split(float x, unsigned short& hi, unsigned short& lo) {
    unsigned u = __float_as_uint(x);
    unsigned r = (u + 0x7FFFu + ((u >> 16) & 1u)) >> 16;   // RNE to bf16
    hi = (unsigned short)r;
    float hf = __uint_as_float(r << 16);
    unsigned u2 = __float_as_uint(x - hf);                 // exact residual
    unsigned r2 = (u2 + 0x7FFFu + ((u2 >> 16) & 1u)) >> 16;
    lo = (unsigned short)r2;
}

__device__ __forceinline__ void split2(float a, float b, unsigned& hw, unsigned& lw) {
    unsigned ua = __float_as_uint(a);
    unsigned ra = (ua + 0x7FFFu + ((ua >> 16) & 1u)) >> 16;
    unsigned ua2 = __float_as_uint(a - __uint_as_float(ra << 16));
    unsigned la = (ua2 + 0x7FFFu + ((ua2 >> 16) & 1u)) >> 16;
    unsigned ub = __float_as_uint(b);
    unsigned rb = (ub + 0x7FFFu + ((ub >> 16) & 1u)) >> 16;
    unsigned ub2 = __float_as_uint(b - __uint_as_float(rb << 16));
    unsigned lb = (ub2 + 0x7FFFu + ((ub2 >> 16) & 1u)) >> 16;
    hw = ra | (rb << 16);
    lw = la | (lb << 16);
}

// ---------------- fused: zero output + weight pre-pack (one launch) ----------------
__global__ void zero_pack(const float* __restrict__ W1, const float* __restrict__ W2,
                          unsigned short* __restrict__ pw,
                          float* __restrict__ out, int out_size) {
    int s = blockIdx.x * blockDim.x + threadIdx.x;
    if (s < out_size) out[s] = 0.f;
    if (s >= PW_SLOTS) return;
    int slot, NS, hiOff, loOff; const float* src; bool tr;
    if (s < 8192)       { slot = s;         NS = 8; hiOff = PW1_HI;  loOff = PW1_LO;  tr = false; src = W1; }
    else if (s < 24576) { slot = s - 8192;  NS = 8; hiOff = PW2_HI;  loOff = PW2_LO;  tr = false; src = W2; }
    else if (s < 40960) { slot = s - 24576; NS = 8; hiOff = PW2T_HI; loOff = PW2T_LO; tr = true;  src = W2; }
    else                { slot = s - 40960; NS = 4; hiOff = PW1T_HI; loOff = PW1T_LO; tr = true;  src = W1; }
    int j = slot & 7, lane = (slot >> 3) & 63, rest = slot >> 9;
    int ns = rest % NS, ks = rest / NS;
    int k = ks * 32 + ((lane >> 4) & 3) * 8 + j;
    int n = ns * 16 + (lane & 15);
    float v = tr ? src[n * 128 + k] : src[k * 128 + n];
    unsigned short hi, lo;
    bf16split(v, hi, lo);
    pw[hiOff + slot] = hi;
    pw[loOff + slot] = lo;
}

// ---------------- fused MLP fwd+bwd via MFMA (R17 config — best measured) ----------------
__global__ __launch_bounds__(256, 2) void mlp_mfma(
    const float* __restrict__ x,
    const float* __restrict__ b1, const float* __restrict__ b2,
    const float* __restrict__ W3, const float* __restrict__ b3,
    const int* __restrict__ indices,
    const unsigned short* __restrict__ pw,
    float* __restrict__ energy, float* __restrict__ dEdD, int natoms)
{
    __shared__ float xs[TT * 64];     // 8 KB, chunk-XOR swizzled (key = row&7)
    __shared__ float h1s[TT * 128];   // 16 KB: h1, overwritten in-place by dz1
    __shared__ float g2s[TT * 128];   // 16 KB

    const int tid = threadIdx.x;
    const int l   = tid & 63;
    const int w   = tid >> 6;
    const int col = l & 15;
    const int rg  = l >> 4;
    const int msub = w >> 1;
    const int half = w & 1;
    const int a0 = blockIdx.x * TT;
    const int mrow = msub * 16 + col;

    #pragma unroll
    for (int p = 0; p < 2; ++p) {
        int idx = tid + p * 256;
        int r = idx >> 4, c = idx & 15;
        int a = a0 + r;
        f32x4 v = {0.f, 0.f, 0.f, 0.f};
        if (a < natoms) v = *(const f32x4*)(x + (size_t)a * 64 + c * 4);
        *(f32x4*)(xs + r * 64 + ((c ^ (r & 7)) << 2)) = v;
    }
    __syncthreads();

    auto loadA = [&](const float* buf, int stride, int kbase, bf16x8& ah, bf16x8& al) {
        int key = mrow & 7;
        int c0 = kbase >> 2;
        f32x4 f0 = *(const f32x4*)(buf + mrow * stride + (((c0    ) ^ key) << 2));
        f32x4 f1 = *(const f32x4*)(buf + mrow * stride + (((c0 + 1) ^ key) << 2));
        u32x4 H, L;
        unsigned hw, lw;
        split2(f0[0], f0[1], hw, lw); H[0] = hw; L[0] = lw;
        split2(f0[2], f0[3], hw, lw); H[1] = hw; L[1] = lw;
        split2(f1[0], f1[1], hw, lw); H[2] = hw; L[2] = lw;
        split2(f1[2], f1[3], hw, lw); H[3] = hw; L[3] = lw;
        ah = __builtin_bit_cast(bf16x8, H);
        al = __builtin_bit_cast(bf16x8, L);
    };
    auto loadB = [&](int hiOff, int loOff, int NS, int ks, int nsub, bf16x8& bh, bf16x8& bl) {
        size_t idx = ((size_t)(ks * NS + nsub) * 64 + l) * 8;
        bh = __builtin_bit_cast(bf16x8, *(const u32x4*)(pw + hiOff + idx));
        bl = __builtin_bit_cast(bf16x8, *(const u32x4*)(pw + loOff + idx));
    };

    // named A-fragments (never in an indexable array)
    bf16x8 ah0, al0, ah1, al1, ah2, al2, ah3, al3;

    #define KSTEP(HIOFF, LOOFF, NS, KS, NSUB, AH, AL)                              \
        {                                                                          \
            bf16x8 bh, bl;                                                         \
            loadB(HIOFF, LOOFF, NS, KS, NSUB, bh, bl);                             \
            acc = __builtin_amdgcn_mfma_f32_16x16x32_bf16(AH, bh, acc, 0, 0, 0);   \
            acc = __builtin_amdgcn_mfma_f32_16x16x32_bf16(AL, bh, acc, 0, 0, 0);   \
            acc = __builtin_amdgcn_mfma_f32_16x16x32_bf16(AH, bl, acc, 0, 0, 0);   \
        }

    // ---- GEMM1: z1 = X@W1 + b1; h1 = sigm ----
    loadA(xs, 64,  0 + rg * 8, ah0, al0);
    loadA(xs, 64, 32 + rg * 8, ah1, al1);
    #pragma unroll
    for (int ns = 0; ns < 4; ++ns) {
        int nsub = half * 4 + ns, n0 = nsub * 16;
        float bv = b1[n0 + col];
        f32x4 acc = {bv, bv, bv, bv};
        KSTEP(PW1_HI, PW1_LO, 8, 0, nsub, ah0, al0)
        KSTEP(PW1_HI, PW1_LO, 8, 1, nsub, ah1, al1)
        #pragma unroll
        for (int r2 = 0; r2 < 4; ++r2) {
            int m = msub * 16 + rg * 4 + r2, k = n0 + col;
            float h = 1.f / (1.f + expf(-acc[r2]));
            h1s[m * 128 + ((((k >> 2)) ^ (m & 7)) << 2) + (k & 3)] = h;
        }
    }
    __syncthreads();

    // ---- GEMM2: z2 = h1@W2 + b2; h2, energy, g2 ----
    loadA(h1s, 128,  0 + rg * 8, ah0, al0);
    loadA(h1s, 128, 32 + rg * 8, ah1, al1);
    loadA(h1s, 128, 64 + rg * 8, ah2, al2);
    loadA(h1s, 128, 96 + rg * 8, ah3, al3);
    float e0 = 0.f, e1 = 0.f, e2 = 0.f, e3 = 0.f;
    #pragma unroll
    for (int ns = 0; ns < 4; ++ns) {
        int nsub = half * 4 + ns, n0 = nsub * 16;
        float bv = b2[n0 + col];
        f32x4 acc = {bv, bv, bv, bv};
        KSTEP(PW2_HI, PW2_LO, 8, 0, nsub, ah0, al0)
        KSTEP(PW2_HI, PW2_LO, 8, 1, nsub, ah1, al1)
        KSTEP(PW2_HI, PW2_LO, 8, 2, nsub, ah2, al2)
        KSTEP(PW2_HI, PW2_LO, 8, 3, nsub, ah3, al3)
        float w3v = W3[n0 + col];
        #pragma unroll
        for (int r2 = 0; r2 < 4; ++r2) {
            float h2 = 1.f / (1.f + expf(-acc[r2]));
            float ec = h2 * w3v;
            if (r2 == 0) e0 += ec; else if (r2 == 1) e1 += ec;
            else if (r2 == 2) e2 += ec; else e3 += ec;
            float g = w3v * h2 * (1.f - h2);
            int m = msub * 16 + rg * 4 + r2, k = n0 + col;
            g2s[m * 128 + ((((k >> 2)) ^ (m & 7)) << 2) + (k & 3)] = g;
        }
    }
    {
        e0 += __shfl_xor(e0, 1); e0 += __shfl_xor(e0, 2); e0 += __shfl_xor(e0, 4); e0 += __shfl_xor(e0, 8);
        e1 += __shfl_xor(e1, 1); e1 += __shfl_xor(e1, 2); e1 += __shfl_xor(e1, 4); e1 += __shfl_xor(e1, 8);
        e2 += __shfl_xor(e2, 1); e2 += __shfl_xor(e2, 2); e2 += __shfl_xor(e2, 4); e2 += __shfl_xor(e2, 8);
        e3 += __shfl_xor(e3, 1); e3 += __shfl_xor(e3, 2); e3 += __shfl_xor(e3, 4); e3 += __shfl_xor(e3, 8);
        if (col == 0) {
            float b3v = (half == 0) ? b3[0] : 0.f;
            int ab = a0 + msub * 16 + rg * 4;
            if (ab + 0 < natoms) atomicAdd(&energy[indices[ab + 0]], e0 + b3v);
            if (ab + 1 < natoms) atomicAdd(&energy[indices[ab + 1]], e1 + b3v);
            if (ab + 2 < natoms) atomicAdd(&energy[indices[ab + 2]], e2 + b3v);
            if (ab + 3 < natoms) atomicAdd(&energy[indices[ab + 3]], e3 + b3v);
        }
    }
    __syncthreads();

    // ---- GEMM3: dh1 = g2@W2^T; dz1 = dh1*h1*(1-h1) in-place ----
    loadA(g2s, 128,  0 + rg * 8, ah0, al0);
    loadA(g2s, 128, 32 + rg * 8, ah1, al1);
    loadA(g2s, 128, 64 + rg * 8, ah2, al2);
    loadA(g2s, 128, 96 + rg * 8, ah3, al3);
    #pragma unroll
    for (int ns = 0; ns < 4; ++ns) {
        int nsub = half * 4 + ns, n0 = nsub * 16;
        f32x4 acc = {0.f, 0.f, 0.f, 0.f};
        KSTEP(PW2T_HI, PW2T_LO, 8, 0, nsub, ah0, al0)
        KSTEP(PW2T_HI, PW2T_LO, 8, 1, nsub, ah1, al1)
        KSTEP(PW2T_HI, PW2T_LO, 8, 2, nsub, ah2, al2)
        KSTEP(PW2T_HI, PW2T_LO, 8, 3, nsub, ah3, al3)
        #pragma unroll
        for (int r2 = 0; r2 < 4; ++r2) {
            int m = msub * 16 + rg * 4 + r2, k = n0 + col;
            int off = m * 128 + ((((k >> 2)) ^ (m & 7)) << 2) + (k & 3);
            float hv = h1s[off];
            h1s[off] = acc[r2] * hv * (1.f - hv);
        }
    }
    __syncthreads();

    // ---- GEMM4: dEdD = dz1@W1^T ----
    loadA(h1s, 128,  0 + rg * 8, ah0, al0);
    loadA(h1s, 128, 32 + rg * 8, ah1, al1);
    loadA(h1s, 128, 64 + rg * 8, ah2, al2);
    loadA(h1s, 128, 96 + rg * 8, ah3, al3);
    #pragma unroll
    for (int ns = 0; ns < 2; ++ns) {
        int nsub = half * 2 + ns, n0 = nsub * 16;
        f32x4 acc = {0.f, 0.f, 0.f, 0.f};
        KSTEP(PW1T_HI, PW1T_LO, 4, 0, nsub, ah0, al0)
        KSTEP(PW1T_HI, PW1T_LO, 4, 1, nsub, ah1, al1)
        KSTEP(PW1T_HI, PW1T_LO, 4, 2, nsub, ah2, al2)
        KSTEP(PW1T_HI, PW1T_LO, 4, 3, nsub, ah3, al3)
        #pragma unroll
        for (int r2 = 0; r2 < 4; ++r2) {
            int a = a0 + msub * 16 + rg * 4 + r2;
            if (a < natoms) dEdD[(size_t)a * 64 + n0 + col] = acc[r2];
        }
    }
    #undef KSTEP
}

// ---------------- force accumulation: 2-group unroll for 2x in-flight bytes ----------------
// R19 pivot: force was 68us @4.7TB/s (75% of achievable). Each iter now issues
// 4 independent 16B loads (2 groups) before any reduce; the two shfl chains
// interleave -> doubled memory-level parallelism per wave.
__global__ __launch_bounds__(256) void force_kernel(
    const float* __restrict__ xd,
    const int* __restrict__ unique_i, const int* __restrict__ unique_j,
    const float* __restrict__ dEdD,
    float* __restrict__ forces, int nderiv)
{
    const int tid = threadIdx.x;
    const int lane = tid & 63;
    const int wib = tid >> 6;
    const int gwave = blockIdx.x * 4 + wib;
    const int nwaves = gridDim.x * 4;
    const int sub = lane >> 4;
    const int t = lane & 15;
    const int ngroups = (nderiv + 3) >> 2;

    for (int g = gwave; g < ngroups; g += 2 * nwaves) {
        const int gB = g + nwaves;
        float p0 = 0.f, p1 = 0.f;
        int j0 = 0, x0 = 0, j1 = 0, x1 = 0;
        bool v0 = false, v1 = false;
        {
            const int r = g * 4 + sub;
            v0 = (r < nderiv);
            if (v0) {
                const int ai = unique_i[r];
                const float4 v = ((const float4*)(xd   + (size_t)r  * 64))[t];
                const float4 wv = ((const float4*)(dEdD + (size_t)ai * 64))[t];
                p0 = v.x * wv.x + v.y * wv.y + v.z * wv.z + v.w * wv.w;
                j0 = unique_j[r];
                x0 = r % 3;   // axis = tile([0,1,2]) by construction
            }
        }
        if (gB < ngroups) {
            const int r = gB * 4 + sub;
            v1 = (r < nderiv);
            if (v1) {
                const int ai = unique_i[r];
                const float4 v = ((const float4*)(xd   + (size_t)r  * 64))[t];
                const float4 wv = ((const float4*)(dEdD + (size_t)ai * 64))[t];
                p1 = v.x * wv.x + v.y * wv.y + v.z * wv.z + v.w * wv.w;
                j1 = unique_j[r];
                x1 = r % 3;
            }
        }
        p0 += __shfl_xor(p0, 1); p1 += __shfl_xor(p1, 1);
        p0 += __shfl_xor(p0, 2); p1 += __shfl_xor(p1, 2);
        p0 += __shfl_xor(p0, 4); p1 += __shfl_xor(p1, 4);
        p0 += __shfl_xor(p0, 8); p1 += __shfl_xor(p1, 8);
        if (t == 0 && v0) atomicAdd(&forces[j0 * 3 + x0], p0);
        if (t == 0 && v1) atomicAdd(&forces[j1 * 3 + x1], p1);
    }
}

extern "C" void kernel_launch(void* const* d_in, const int* in_sizes, int n_in,
                              void* d_out, int out_size, void* d_ws, size_t ws_size,
                              hipStream_t stream) {
    const float* x        = (const float*)d_in[0];
    const float* xd       = (const float*)d_in[1];
    const int*   indices  = (const int*)d_in[2];
    const int*   unique_i = (const int*)d_in[6];
    const int*   unique_j = (const int*)d_in[7];
    const float* W1       = (const float*)d_in[8];
    const float* b1       = (const float*)d_in[9];
    const float* W2       = (const float*)d_in[10];
    const float* b2       = (const float*)d_in[11];
    const float* W3       = (const float*)d_in[12];
    const float* b3       = (const float*)d_in[13];

    const int natoms = in_sizes[2];
    const int nconf  = in_sizes[3];
    const int nderiv = in_sizes[6];

    float* out    = (float*)d_out;
    float* energy = out;
    float* forces = out + nconf;
    float* dEdD   = (float*)d_ws;
    unsigned short* pw = (unsigned short*)((char*)d_ws + (size_t)natoms * 64 * 4);

    const int ntiles = (natoms + TT - 1) / TT;
    const int zp_n = (out_size > PW_SLOTS) ? out_size : PW_SLOTS;

    zero_pack<<<(zp_n + 255) / 256, 256, 0, stream>>>(W1, W2, pw, out, out_size);
    mlp_mfma<<<ntiles, 256, 0, stream>>>(x, b1, b2, W3, b3, indices, pw,
                                         energy, dEdD, natoms);
    force_kernel<<<2048, 256, 0, stream>>>(xd, unique_i, unique_j, dEdD,
                                           forces, nderiv);
}